// Round 4
// baseline (168.367 us; speedup 1.0000x reference)
//
#include <hip/hip_runtime.h>

// MipRayMarcher2: NeuS-style alpha compositing.
// Block = 256 threads = 16 rays (16 lanes/ray, 3 samples/lane).
// Global<->LDS transpose: all global traffic is coalesced float4; the
// divergent stride-36B sample access pattern is served by LDS (2-way bank
// aliasing only = free). Cross-lane via DPP row ops (16-lane rows).

static constexpr int NRAYS = 65536;          // B*R = 4*16384
static constexpr int SM = 47;
static constexpr int OFF_DEPTH  = NRAYS * 3;             // 196608
static constexpr int OFF_W      = OFF_DEPTH + NRAYS;     // 262144
static constexpr int OFF_NORMAL = OFF_W + NRAYS * SM;    // 3342336

struct F3 { float x, y, z; };

template <int CTRL>
__device__ __forceinline__ float dpp_mov(float x, float old) {
    return __builtin_bit_cast(float,
        __builtin_amdgcn_update_dpp(__builtin_bit_cast(int, old),
                                    __builtin_bit_cast(int, x),
                                    CTRL, 0xF, 0xF, false));
}
#define ROW_SHL1 0x101       // lane i <- lane i+1 within 16-lane row
#define ROW_SHR(n) (0x110 + (n))
#define ROW_ROR(n) (0x120 + (n))

__device__ __forceinline__ float row_nbr(float x) {
    return dpp_mov<ROW_SHL1>(x, x);          // lane15 keeps own (masked later)
}
__device__ __forceinline__ float row_sum16(float x) {
    x += dpp_mov<ROW_ROR(8)>(x, 0.0f);
    x += dpp_mov<ROW_ROR(4)>(x, 0.0f);
    x += dpp_mov<ROW_ROR(2)>(x, 0.0f);
    x += dpp_mov<ROW_ROR(1)>(x, 0.0f);
    return x;
}

__global__ __launch_bounds__(256) void march_kernel(
    const float* __restrict__ colors,
    const float* __restrict__ sdfs,
    const float* __restrict__ depths,
    const float* __restrict__ normals,
    const float* __restrict__ ray_dirs,
    const float* __restrict__ real_normals,
    const float* __restrict__ inv_std_p,
    float* __restrict__ out)
{
    __shared__ alignas(16) float s_c[2304];   // 16 rays x 48 x 3
    __shared__ alignas(16) float s_n[2304];
    __shared__ alignas(16) float s_r[2304];
    __shared__ alignas(16) float s_sd[768];   // 16 x 48
    __shared__ alignas(16) float s_dp[768];
    __shared__ alignas(16) float s_dir[48];   // 16 x 3
    __shared__ alignas(16) float s_w[752];    // 16 x 47

    const int tid  = threadIdx.x;
    const int ray0 = blockIdx.x * 16;

    // ---- Stage inputs: perfectly coalesced float4 streams ----
    {
        const float4* gc = (const float4*)(colors       + (size_t)ray0 * 144);
        const float4* gn = (const float4*)(normals      + (size_t)ray0 * 144);
        const float4* gr = (const float4*)(real_normals + (size_t)ray0 * 144);
        const float4* gs = (const float4*)(sdfs         + (size_t)ray0 * 48);
        const float4* gd = (const float4*)(depths       + (size_t)ray0 * 48);
        float4* sc = (float4*)s_c;
        float4* sn = (float4*)s_n;
        float4* sr = (float4*)s_r;
        float4* ss = (float4*)s_sd;
        float4* sd = (float4*)s_dp;
#pragma unroll
        for (int k = 0; k < 3; ++k) {
            const int i = tid + k * 256;
            if (i < 576) { sc[i] = gc[i]; sn[i] = gn[i]; sr[i] = gr[i]; }
        }
        if (tid < 192) { ss[tid] = gs[tid]; sd[tid] = gd[tid]; }
        if (tid < 12) ((float4*)s_dir)[tid] = ((const float4*)(ray_dirs + (size_t)ray0 * 3))[tid];
    }
    __syncthreads();

    const int localRay = tid >> 4;            // 0..15
    const int sl       = tid & 15;            // sub-lane (DPP row position)
    const int ray      = ray0 + localRay;

    // Wave-uniform constants; fold log2(e) and the 0.5 midpoint scaling.
    const float L2E = 1.4426950408889634f;
    const float inv_std = fminf(fmaxf(__expf(inv_std_p[0] * 10.0f), 1e-6f), 1e6f);
    const float uu = inv_std * (0.5f  * L2E);
    const float qq = inv_std * (0.25f * L2E);

    const F3 dir = *(const F3*)(s_dir + localRay * 3);

    const int cb = localRay * 144 + sl * 9;   // float idx into s_c/s_n/s_r
    const int sb = localRay * 48 + sl * 3;    // float idx into s_sd/s_dp

    const F3 sd3 = *(const F3*)(s_sd + sb);
    const F3 dp3 = *(const F3*)(s_dp + sb);
    F3 c[3], n[3], r[3];
#pragma unroll
    for (int j = 0; j < 3; ++j) {
        c[j] = *(const F3*)(s_c + cb + 3 * j);
        n[j] = *(const F3*)(s_n + cb + 3 * j);
        r[j] = *(const F3*)(s_r + cb + 3 * j);
    }

    // Neighbor lane's first sample via DPP.
    const float sdN = row_nbr(sd3.x);
    const float dpN = row_nbr(dp3.x);
    const float c0N = row_nbr(c[0].x);
    const float c1N = row_nbr(c[0].y);
    const float c2N = row_nbr(c[0].z);
    const float n0N = row_nbr(n[0].x);
    const float n1N = row_nbr(n[0].y);
    const float n2N = row_nbr(n[0].z);
    const float r0N = row_nbr(r[0].x);
    const float r1N = row_nbr(r[0].y);
    const float r2N = row_nbr(r[0].z);

    const float SD[4] = { sd3.x, sd3.y, sd3.z, sdN };
    const float DP[4] = { dp3.x, dp3.y, dp3.z, dpN };
    const float C0[4] = { c[0].x, c[1].x, c[2].x, c0N };
    const float C1[4] = { c[0].y, c[1].y, c[2].y, c1N };
    const float C2[4] = { c[0].z, c[1].z, c[2].z, c2N };
    const float N0[4] = { n[0].x, n[1].x, n[2].x, n0N };
    const float N1[4] = { n[0].y, n[1].y, n[2].y, n1N };
    const float N2[4] = { n[0].z, n[1].z, n[2].z, n2N };
    const float R0[4] = { r[0].x, r[1].x, r[2].x, r0N };
    const float R1[4] = { r[0].y, r[1].y, r[2].y, r1N };
    const float R2[4] = { r[0].z, r[1].z, r[2].z, r2N };

    float al[3], tt[3];
    float cs0[3], cs1[3], cs2[3], dsum[3], rs0[3], rs1[3], rs2[3];

#pragma unroll
    for (int j = 0; j < 3; ++j) {
        const float delta = DP[j + 1] - DP[j];
        cs0[j]  = C0[j] + C0[j + 1];
        cs1[j]  = C1[j] + C1[j + 1];
        cs2[j]  = C2[j] + C2[j + 1];
        dsum[j] = DP[j] + DP[j + 1];
        rs0[j]  = R0[j] + R0[j + 1];
        rs1[j]  = R1[j] + R1[j + 1];
        rs2[j]  = R2[j] + R2[j + 1];
        const float ss  = SD[j] + SD[j + 1];
        const float ns0 = N0[j] + N0[j + 1];
        const float ns1 = N1[j] + N1[j + 1];
        const float ns2 = N2[j] + N2[j + 1];

        const float dots = dir.x * ns0 + dir.y * ns1 + dir.z * ns2;
        const float mn   = fminf(dots, 0.0f);
        const float mq   = mn * delta * qq;
        const float base = ss * uu;
        const float ep = __builtin_amdgcn_exp2f(mq - base);    // prev: 1/(1+ep)
        const float pc = __builtin_amdgcn_rcpf(1.0f + ep);
        const float en = __builtin_amdgcn_exp2f(-(mq + base)); // next: 1/(1+en)
        const float nc = __builtin_amdgcn_rcpf(1.0f + en);

        float a = (pc - nc + 1e-5f) * __builtin_amdgcn_rcpf(pc + 1e-5f);
        a = fminf(fmaxf(a, 0.0f), 1.0f);
        const bool valid = (j < 2) | (sl < 15);   // interval 47 doesn't exist
        if (!valid) a = 0.0f;
        al[j] = a;
        tt[j] = 1.0f - a + 1e-10f;
    }

    // Inclusive multiply-scan across the 16-lane row (identity = 1.0).
    float p = tt[0] * tt[1] * tt[2];
    p *= dpp_mov<ROW_SHR(1)>(p, 1.0f);
    p *= dpp_mov<ROW_SHR(2)>(p, 1.0f);
    p *= dpp_mov<ROW_SHR(4)>(p, 1.0f);
    p *= dpp_mov<ROW_SHR(8)>(p, 1.0f);
    const float excl = dpp_mov<ROW_SHR(1)>(p, 1.0f);

    const float T0 = excl;
    const float T1 = excl * tt[0];
    const float T2 = T1 * tt[1];
    const float w0 = al[0] * T0;
    const float w1 = al[1] * T1;
    const float w2 = al[2] * T2;

    // Per-lane partials (cs/dsum/rs are 2x the mids; fixed in epilogue).
    float ws  = w0 + w1 + w2;
    float sc0 = w0 * cs0[0] + w1 * cs0[1] + w2 * cs0[2];
    float sc1 = w0 * cs1[0] + w1 * cs1[1] + w2 * cs1[2];
    float sc2 = w0 * cs2[0] + w1 * cs2[1] + w2 * cs2[2];
    float sdp = w0 * dsum[0] + w1 * dsum[1] + w2 * dsum[2];
    float sr0 = w0 * rs0[0] + w1 * rs0[1] + w2 * rs0[2];
    float sr1 = w0 * rs1[0] + w1 * rs1[1] + w2 * rs1[2];
    float sr2 = w0 * rs2[0] + w1 * rs2[1] + w2 * rs2[2];

    ws  = row_sum16(ws);
    sc0 = row_sum16(sc0);
    sc1 = row_sum16(sc1);
    sc2 = row_sum16(sc2);
    sdp = row_sum16(sdp);
    sr0 = row_sum16(sr0);
    sr1 = row_sum16(sr1);
    sr2 = row_sum16(sr2);

    // Weights -> LDS (then coalesced copy-out).
    const int wb = localRay * 47 + sl * 3;
    s_w[wb + 0] = w0;
    s_w[wb + 1] = w1;
    if (sl < 15) s_w[wb + 2] = w2;

    // Small per-ray outputs: direct stores from sl==0.
    if (sl == 0) {
        out[ray * 3 + 0] = 0.5f * sc0;
        out[ray * 3 + 1] = 0.5f * sc1;
        out[ray * 3 + 2] = 0.5f * sc2;
        const float hiw = 0.5f * __builtin_amdgcn_rcpf(ws);  // ws >= ~5e-6 always
        out[OFF_DEPTH + ray] = sdp * hiw;
        out[OFF_NORMAL + ray * 3 + 0] = sr0 * hiw;
        out[OFF_NORMAL + ray * 3 + 1] = sr1 * hiw;
        out[OFF_NORMAL + ray * 3 + 2] = sr2 * hiw;
    }

    __syncthreads();

    // Coalesced weights write: 16 rays x 47 floats = 752 floats = 188 float4.
    if (tid < 188) {
        float4* gw = (float4*)(out + OFF_W + (size_t)ray0 * 47);
        gw[tid] = ((const float4*)s_w)[tid];
    }
}

extern "C" void kernel_launch(void* const* d_in, const int* in_sizes, int n_in,
                              void* d_out, int out_size, void* d_ws, size_t ws_size,
                              hipStream_t stream) {
    const float* colors       = (const float*)d_in[0];
    const float* sdfs         = (const float*)d_in[1];
    const float* depths       = (const float*)d_in[2];
    const float* normals      = (const float*)d_in[3];
    const float* ray_dirs     = (const float*)d_in[4];
    const float* real_normals = (const float*)d_in[5];
    const float* inv_std_p    = (const float*)d_in[6];
    float* out = (float*)d_out;

    dim3 grid(NRAYS / 16);   // 4096 blocks, 16 rays per block
    dim3 block(256);
    hipLaunchKernelGGL(march_kernel, grid, block, 0, stream,
                       colors, sdfs, depths, normals, ray_dirs, real_normals,
                       inv_std_p, out);
}

// Round 5
// 166.703 us; speedup vs baseline: 1.0100x; 1.0100x over previous
//
#include <hip/hip_runtime.h>

// MipRayMarcher2: NeuS-style alpha compositing.
// 4 rays per wave: 16 lanes/ray, 3 samples/lane (S=48, intervals SM=47).
// No LDS, no barriers. All 12 global loads issued up-front (sched_barrier
// pins them before any consume) for deep per-wave memory-level parallelism;
// cross-lane via DPP row ops (16-lane rows = ray groups).

static constexpr int NRAYS = 65536;          // B*R = 4*16384
static constexpr int SM = 47;
static constexpr int OFF_DEPTH  = NRAYS * 3;             // 196608
static constexpr int OFF_W      = OFF_DEPTH + NRAYS;     // 262144
static constexpr int OFF_NORMAL = OFF_W + NRAYS * SM;    // 3342336

struct F3 { float x, y, z; };

template <int CTRL>
__device__ __forceinline__ float dpp_mov(float x, float old) {
    return __builtin_bit_cast(float,
        __builtin_amdgcn_update_dpp(__builtin_bit_cast(int, old),
                                    __builtin_bit_cast(int, x),
                                    CTRL, 0xF, 0xF, false));
}
#define ROW_SHL1 0x101       // lane i <- lane i+1 within 16-lane row
#define ROW_SHR(n) (0x110 + (n))
#define ROW_ROR(n) (0x120 + (n))

__device__ __forceinline__ float row_nbr(float x) {
    return dpp_mov<ROW_SHL1>(x, x);          // lane15 keeps own (masked later)
}
__device__ __forceinline__ float row_sum16(float x) {
    x += dpp_mov<ROW_ROR(8)>(x, 0.0f);
    x += dpp_mov<ROW_ROR(4)>(x, 0.0f);
    x += dpp_mov<ROW_ROR(2)>(x, 0.0f);
    x += dpp_mov<ROW_ROR(1)>(x, 0.0f);
    return x;
}

__global__ __launch_bounds__(256) void march_kernel(
    const float* __restrict__ colors,
    const float* __restrict__ sdfs,
    const float* __restrict__ depths,
    const float* __restrict__ normals,
    const float* __restrict__ ray_dirs,
    const float* __restrict__ real_normals,
    const float* __restrict__ inv_std_p,
    float* __restrict__ out)
{
    const int tid = blockIdx.x * 256 + threadIdx.x;
    const int ray = tid >> 4;                 // 16 lanes per ray
    const int sl  = threadIdx.x & 15;         // sub-lane (DPP row position)

    const int sbase = ray * 16 + sl;          // F3 index into sdfs/depths
    const int cbase = ray * 48 + sl * 3;      // F3 index into colors/normals/real_normals

    // ---------------- LOAD PHASE: 12 independent vmem ops ----------------
    const float istdp = inv_std_p[0];
    const F3 dir = ((const F3*)ray_dirs)[ray];
    const F3 sd3 = ((const F3*)sdfs)[sbase];
    const F3 dp3 = ((const F3*)depths)[sbase];
    F3 c[3], n[3], r[3];
#pragma unroll
    for (int j = 0; j < 3; ++j) {
        c[j] = ((const F3*)colors)[cbase + j];
        n[j] = ((const F3*)normals)[cbase + j];
        r[j] = ((const F3*)real_normals)[cbase + j];
    }
    // Nothing below may be hoisted above; all loads stay batched in flight.
    __builtin_amdgcn_sched_barrier(0);
    // ---------------------------------------------------------------------

    // Wave-uniform constants; fold log2(e) and the 0.5 midpoint scaling.
    const float L2E = 1.4426950408889634f;
    const float inv_std = fminf(fmaxf(__expf(istdp * 10.0f), 1e-6f), 1e6f);
    const float uu = inv_std * (0.5f  * L2E);
    const float qq = inv_std * (0.25f * L2E);

    // Neighbor lane's first sample via DPP.
    const float sdN = row_nbr(sd3.x);
    const float dpN = row_nbr(dp3.x);
    const float c0N = row_nbr(c[0].x);
    const float c1N = row_nbr(c[0].y);
    const float c2N = row_nbr(c[0].z);
    const float n0N = row_nbr(n[0].x);
    const float n1N = row_nbr(n[0].y);
    const float n2N = row_nbr(n[0].z);
    const float r0N = row_nbr(r[0].x);
    const float r1N = row_nbr(r[0].y);
    const float r2N = row_nbr(r[0].z);

    const float SD[4] = { sd3.x, sd3.y, sd3.z, sdN };
    const float DP[4] = { dp3.x, dp3.y, dp3.z, dpN };
    const float C0[4] = { c[0].x, c[1].x, c[2].x, c0N };
    const float C1[4] = { c[0].y, c[1].y, c[2].y, c1N };
    const float C2[4] = { c[0].z, c[1].z, c[2].z, c2N };
    const float N0[4] = { n[0].x, n[1].x, n[2].x, n0N };
    const float N1[4] = { n[0].y, n[1].y, n[2].y, n1N };
    const float N2[4] = { n[0].z, n[1].z, n[2].z, n2N };
    const float R0[4] = { r[0].x, r[1].x, r[2].x, r0N };
    const float R1[4] = { r[0].y, r[1].y, r[2].y, r1N };
    const float R2[4] = { r[0].z, r[1].z, r[2].z, r2N };

    float al[3], tt[3];
    float cs0[3], cs1[3], cs2[3], dsum[3], rs0[3], rs1[3], rs2[3];

#pragma unroll
    for (int j = 0; j < 3; ++j) {
        const float delta = DP[j + 1] - DP[j];
        cs0[j]  = C0[j] + C0[j + 1];
        cs1[j]  = C1[j] + C1[j + 1];
        cs2[j]  = C2[j] + C2[j + 1];
        dsum[j] = DP[j] + DP[j + 1];
        rs0[j]  = R0[j] + R0[j + 1];
        rs1[j]  = R1[j] + R1[j + 1];
        rs2[j]  = R2[j] + R2[j + 1];
        const float ss  = SD[j] + SD[j + 1];
        const float ns0 = N0[j] + N0[j + 1];
        const float ns1 = N1[j] + N1[j + 1];
        const float ns2 = N2[j] + N2[j + 1];

        const float dots = dir.x * ns0 + dir.y * ns1 + dir.z * ns2;
        const float mn   = fminf(dots, 0.0f);
        const float mq   = mn * delta * qq;
        const float base = ss * uu;
        const float ep = __builtin_amdgcn_exp2f(mq - base);    // prev: 1/(1+ep)
        const float pc = __builtin_amdgcn_rcpf(1.0f + ep);
        const float en = __builtin_amdgcn_exp2f(-(mq + base)); // next: 1/(1+en)
        const float nc = __builtin_amdgcn_rcpf(1.0f + en);

        float a = (pc - nc + 1e-5f) * __builtin_amdgcn_rcpf(pc + 1e-5f);
        a = fminf(fmaxf(a, 0.0f), 1.0f);
        const bool valid = (j < 2) | (sl < 15);   // interval 47 doesn't exist
        if (!valid) a = 0.0f;
        al[j] = a;
        tt[j] = 1.0f - a + 1e-10f;
    }

    // Inclusive multiply-scan across the 16-lane row (identity = 1.0).
    float p = tt[0] * tt[1] * tt[2];
    p *= dpp_mov<ROW_SHR(1)>(p, 1.0f);
    p *= dpp_mov<ROW_SHR(2)>(p, 1.0f);
    p *= dpp_mov<ROW_SHR(4)>(p, 1.0f);
    p *= dpp_mov<ROW_SHR(8)>(p, 1.0f);
    const float excl = dpp_mov<ROW_SHR(1)>(p, 1.0f);

    const float T0 = excl;
    const float T1 = excl * tt[0];
    const float T2 = T1 * tt[1];
    const float w0 = al[0] * T0;
    const float w1 = al[1] * T1;
    const float w2 = al[2] * T2;

    // Per-lane partials (cs/dsum/rs are 2x the mids; fixed in epilogue).
    float ws  = w0 + w1 + w2;
    float sc0 = w0 * cs0[0] + w1 * cs0[1] + w2 * cs0[2];
    float sc1 = w0 * cs1[0] + w1 * cs1[1] + w2 * cs1[2];
    float sc2 = w0 * cs2[0] + w1 * cs2[1] + w2 * cs2[2];
    float sdp = w0 * dsum[0] + w1 * dsum[1] + w2 * dsum[2];
    float sr0 = w0 * rs0[0] + w1 * rs0[1] + w2 * rs0[2];
    float sr1 = w0 * rs1[0] + w1 * rs1[1] + w2 * rs1[2];
    float sr2 = w0 * rs2[0] + w1 * rs2[1] + w2 * rs2[2];

    ws  = row_sum16(ws);
    sc0 = row_sum16(sc0);
    sc1 = row_sum16(sc1);
    sc2 = row_sum16(sc2);
    sdp = row_sum16(sdp);
    sr0 = row_sum16(sr0);
    sr1 = row_sum16(sr1);
    sr2 = row_sum16(sr2);

    // Weights output (intervals 3*sl .. 3*sl+2).
    const int wbase = OFF_W + ray * SM + sl * 3;
    out[wbase + 0] = w0;
    out[wbase + 1] = w1;
    if (sl < 15) out[wbase + 2] = w2;

    if (sl == 0) {
        out[ray * 3 + 0] = 0.5f * sc0;
        out[ray * 3 + 1] = 0.5f * sc1;
        out[ray * 3 + 2] = 0.5f * sc2;
        const float hiw = 0.5f * __builtin_amdgcn_rcpf(ws);  // ws >= ~5e-6 always
        out[OFF_DEPTH + ray] = sdp * hiw;
        out[OFF_NORMAL + ray * 3 + 0] = sr0 * hiw;
        out[OFF_NORMAL + ray * 3 + 1] = sr1 * hiw;
        out[OFF_NORMAL + ray * 3 + 2] = sr2 * hiw;
    }
}

extern "C" void kernel_launch(void* const* d_in, const int* in_sizes, int n_in,
                              void* d_out, int out_size, void* d_ws, size_t ws_size,
                              hipStream_t stream) {
    const float* colors       = (const float*)d_in[0];
    const float* sdfs         = (const float*)d_in[1];
    const float* depths       = (const float*)d_in[2];
    const float* normals      = (const float*)d_in[3];
    const float* ray_dirs     = (const float*)d_in[4];
    const float* real_normals = (const float*)d_in[5];
    const float* inv_std_p    = (const float*)d_in[6];
    float* out = (float*)d_out;

    dim3 grid(NRAYS * 16 / 256);   // 4096 blocks
    dim3 block(256);
    hipLaunchKernelGGL(march_kernel, grid, block, 0, stream,
                       colors, sdfs, depths, normals, ray_dirs, real_normals,
                       inv_std_p, out);
}

// Round 6
// 166.325 us; speedup vs baseline: 1.0123x; 1.0023x over previous
//
#include <hip/hip_runtime.h>

// MipRayMarcher2: NeuS-style alpha compositing.
// 4 rays per wave: 16 lanes/ray, 3 samples/lane (S=48, intervals SM=47).
// No LDS, no barriers. All 12 global loads forced into one in-flight batch
// via an asm value-pin (compiler cannot serialize: every loaded component is
// an operand). Cross-lane via DPP row ops (16-lane rows = ray groups).

static constexpr int NRAYS = 65536;          // B*R = 4*16384
static constexpr int SM = 47;
static constexpr int OFF_DEPTH  = NRAYS * 3;             // 196608
static constexpr int OFF_W      = OFF_DEPTH + NRAYS;     // 262144
static constexpr int OFF_NORMAL = OFF_W + NRAYS * SM;    // 3342336

struct F3 { float x, y, z; };

template <int CTRL>
__device__ __forceinline__ float dpp_mov(float x, float old) {
    return __builtin_bit_cast(float,
        __builtin_amdgcn_update_dpp(__builtin_bit_cast(int, old),
                                    __builtin_bit_cast(int, x),
                                    CTRL, 0xF, 0xF, false));
}
#define ROW_SHL1 0x101       // lane i <- lane i+1 within 16-lane row
#define ROW_SHR(n) (0x110 + (n))
#define ROW_ROR(n) (0x120 + (n))

__device__ __forceinline__ float row_nbr(float x) {
    return dpp_mov<ROW_SHL1>(x, x);          // lane15 keeps own (masked later)
}
__device__ __forceinline__ float row_sum16(float x) {
    x += dpp_mov<ROW_ROR(8)>(x, 0.0f);
    x += dpp_mov<ROW_ROR(4)>(x, 0.0f);
    x += dpp_mov<ROW_ROR(2)>(x, 0.0f);
    x += dpp_mov<ROW_ROR(1)>(x, 0.0f);
    return x;
}

__global__ __launch_bounds__(256) void march_kernel(
    const float* __restrict__ colors,
    const float* __restrict__ sdfs,
    const float* __restrict__ depths,
    const float* __restrict__ normals,
    const float* __restrict__ ray_dirs,
    const float* __restrict__ real_normals,
    const float* __restrict__ inv_std_p,
    float* __restrict__ out)
{
    const int tid = blockIdx.x * 256 + threadIdx.x;
    const int ray = tid >> 4;                 // 16 lanes per ray
    const int sl  = threadIdx.x & 15;         // sub-lane (DPP row position)

    const int sbase = ray * 16 + sl;          // F3 index into sdfs/depths
    const int cbase = ray * 48 + sl * 3;      // F3 index into colors/normals/real_normals

    // ---------------- LOAD PHASE: 12 independent vmem ops ----------------
    float istdp = inv_std_p[0];
    F3 dir = ((const F3*)ray_dirs)[ray];
    F3 sd3 = ((const F3*)sdfs)[sbase];
    F3 dp3 = ((const F3*)depths)[sbase];
    F3 c0 = ((const F3*)colors)[cbase + 0];
    F3 c1 = ((const F3*)colors)[cbase + 1];
    F3 c2 = ((const F3*)colors)[cbase + 2];
    F3 n0 = ((const F3*)normals)[cbase + 0];
    F3 n1 = ((const F3*)normals)[cbase + 1];
    F3 n2 = ((const F3*)normals)[cbase + 2];
    F3 r0 = ((const F3*)real_normals)[cbase + 0];
    F3 r1 = ((const F3*)real_normals)[cbase + 1];
    F3 r2 = ((const F3*)real_normals)[cbase + 2];

    // Hard pin: every loaded component is an operand of one asm statement.
    // All loads must be issued and completed before this point; none can be
    // sunk into the consume chain. This is the MLP forcer sched_barrier wasn't.
    asm volatile("" :
        "+v"(istdp),
        "+v"(dir.x), "+v"(dir.y), "+v"(dir.z),
        "+v"(sd3.x), "+v"(sd3.y), "+v"(sd3.z),
        "+v"(dp3.x), "+v"(dp3.y), "+v"(dp3.z),
        "+v"(c0.x), "+v"(c0.y), "+v"(c0.z),
        "+v"(c1.x), "+v"(c1.y), "+v"(c1.z),
        "+v"(c2.x), "+v"(c2.y), "+v"(c2.z),
        "+v"(n0.x), "+v"(n0.y), "+v"(n0.z),
        "+v"(n1.x), "+v"(n1.y), "+v"(n1.z),
        "+v"(n2.x), "+v"(n2.y), "+v"(n2.z),
        "+v"(r0.x), "+v"(r0.y), "+v"(r0.z),
        "+v"(r1.x), "+v"(r1.y), "+v"(r1.z),
        "+v"(r2.x), "+v"(r2.y), "+v"(r2.z));
    // ---------------------------------------------------------------------

    // Wave-uniform constants; fold log2(e) and the 0.5 midpoint scaling.
    const float L2E = 1.4426950408889634f;
    const float inv_std = fminf(fmaxf(__expf(istdp * 10.0f), 1e-6f), 1e6f);
    const float uu = inv_std * (0.5f  * L2E);
    const float qq = inv_std * (0.25f * L2E);

    // Neighbor lane's first sample via DPP.
    const float sdN = row_nbr(sd3.x);
    const float dpN = row_nbr(dp3.x);
    const float c0N = row_nbr(c0.x);
    const float c1N = row_nbr(c0.y);
    const float c2N = row_nbr(c0.z);
    const float n0N = row_nbr(n0.x);
    const float n1N = row_nbr(n0.y);
    const float n2N = row_nbr(n0.z);
    const float r0N = row_nbr(r0.x);
    const float r1N = row_nbr(r0.y);
    const float r2N = row_nbr(r0.z);

    const float SD[4] = { sd3.x, sd3.y, sd3.z, sdN };
    const float DP[4] = { dp3.x, dp3.y, dp3.z, dpN };
    const float C0[4] = { c0.x, c1.x, c2.x, c0N };
    const float C1[4] = { c0.y, c1.y, c2.y, c1N };
    const float C2[4] = { c0.z, c1.z, c2.z, c2N };
    const float N0[4] = { n0.x, n1.x, n2.x, n0N };
    const float N1[4] = { n0.y, n1.y, n2.y, n1N };
    const float N2[4] = { n0.z, n1.z, n2.z, n2N };
    const float R0[4] = { r0.x, r1.x, r2.x, r0N };
    const float R1[4] = { r0.y, r1.y, r2.y, r1N };
    const float R2[4] = { r0.z, r1.z, r2.z, r2N };

    float al[3], tt[3];
    float cs0[3], cs1[3], cs2[3], dsum[3], rs0[3], rs1[3], rs2[3];

#pragma unroll
    for (int j = 0; j < 3; ++j) {
        const float delta = DP[j + 1] - DP[j];
        cs0[j]  = C0[j] + C0[j + 1];
        cs1[j]  = C1[j] + C1[j + 1];
        cs2[j]  = C2[j] + C2[j + 1];
        dsum[j] = DP[j] + DP[j + 1];
        rs0[j]  = R0[j] + R0[j + 1];
        rs1[j]  = R1[j] + R1[j + 1];
        rs2[j]  = R2[j] + R2[j + 1];
        const float ss  = SD[j] + SD[j + 1];
        const float ns0 = N0[j] + N0[j + 1];
        const float ns1 = N1[j] + N1[j + 1];
        const float ns2 = N2[j] + N2[j + 1];

        const float dots = dir.x * ns0 + dir.y * ns1 + dir.z * ns2;
        const float mn   = fminf(dots, 0.0f);
        const float mq   = mn * delta * qq;
        const float base = ss * uu;
        const float ep = __builtin_amdgcn_exp2f(mq - base);    // prev: 1/(1+ep)
        const float pc = __builtin_amdgcn_rcpf(1.0f + ep);
        const float en = __builtin_amdgcn_exp2f(-(mq + base)); // next: 1/(1+en)
        const float nc = __builtin_amdgcn_rcpf(1.0f + en);

        float a = (pc - nc + 1e-5f) * __builtin_amdgcn_rcpf(pc + 1e-5f);
        a = fminf(fmaxf(a, 0.0f), 1.0f);
        const bool valid = (j < 2) | (sl < 15);   // interval 47 doesn't exist
        if (!valid) a = 0.0f;
        al[j] = a;
        tt[j] = 1.0f - a + 1e-10f;
    }

    // Inclusive multiply-scan across the 16-lane row (identity = 1.0).
    float p = tt[0] * tt[1] * tt[2];
    p *= dpp_mov<ROW_SHR(1)>(p, 1.0f);
    p *= dpp_mov<ROW_SHR(2)>(p, 1.0f);
    p *= dpp_mov<ROW_SHR(4)>(p, 1.0f);
    p *= dpp_mov<ROW_SHR(8)>(p, 1.0f);
    const float excl = dpp_mov<ROW_SHR(1)>(p, 1.0f);

    const float T0 = excl;
    const float T1 = excl * tt[0];
    const float T2 = T1 * tt[1];
    const float w0 = al[0] * T0;
    const float w1 = al[1] * T1;
    const float w2 = al[2] * T2;

    // Per-lane partials (cs/dsum/rs are 2x the mids; fixed in epilogue).
    float ws  = w0 + w1 + w2;
    float sc0 = w0 * cs0[0] + w1 * cs0[1] + w2 * cs0[2];
    float sc1 = w0 * cs1[0] + w1 * cs1[1] + w2 * cs1[2];
    float sc2 = w0 * cs2[0] + w1 * cs2[1] + w2 * cs2[2];
    float sdp = w0 * dsum[0] + w1 * dsum[1] + w2 * dsum[2];
    float sr0 = w0 * rs0[0] + w1 * rs0[1] + w2 * rs0[2];
    float sr1 = w0 * rs1[0] + w1 * rs1[1] + w2 * rs1[2];
    float sr2 = w0 * rs2[0] + w1 * rs2[1] + w2 * rs2[2];

    ws  = row_sum16(ws);
    sc0 = row_sum16(sc0);
    sc1 = row_sum16(sc1);
    sc2 = row_sum16(sc2);
    sdp = row_sum16(sdp);
    sr0 = row_sum16(sr0);
    sr1 = row_sum16(sr1);
    sr2 = row_sum16(sr2);

    // Weights output (intervals 3*sl .. 3*sl+2).
    const int wbase = OFF_W + ray * SM + sl * 3;
    out[wbase + 0] = w0;
    out[wbase + 1] = w1;
    if (sl < 15) out[wbase + 2] = w2;

    if (sl == 0) {
        out[ray * 3 + 0] = 0.5f * sc0;
        out[ray * 3 + 1] = 0.5f * sc1;
        out[ray * 3 + 2] = 0.5f * sc2;
        const float hiw = 0.5f * __builtin_amdgcn_rcpf(ws);  // ws >= ~5e-6 always
        out[OFF_DEPTH + ray] = sdp * hiw;
        out[OFF_NORMAL + ray * 3 + 0] = sr0 * hiw;
        out[OFF_NORMAL + ray * 3 + 1] = sr1 * hiw;
        out[OFF_NORMAL + ray * 3 + 2] = sr2 * hiw;
    }
}

extern "C" void kernel_launch(void* const* d_in, const int* in_sizes, int n_in,
                              void* d_out, int out_size, void* d_ws, size_t ws_size,
                              hipStream_t stream) {
    const float* colors       = (const float*)d_in[0];
    const float* sdfs         = (const float*)d_in[1];
    const float* depths       = (const float*)d_in[2];
    const float* normals      = (const float*)d_in[3];
    const float* ray_dirs     = (const float*)d_in[4];
    const float* real_normals = (const float*)d_in[5];
    const float* inv_std_p    = (const float*)d_in[6];
    float* out = (float*)d_out;

    dim3 grid(NRAYS * 16 / 256);   // 4096 blocks
    dim3 block(256);
    hipLaunchKernelGGL(march_kernel, grid, block, 0, stream,
                       colors, sdfs, depths, normals, ray_dirs, real_normals,
                       inv_std_p, out);
}